// Round 7
// baseline (158.512 us; speedup 1.0000x reference)
//
#include <hip/hip_runtime.h>
#include <hip/hip_bf16.h>

// EGNN layer, MI355X. B=4, N=256, H=128, E=16, EIN=273. All I/O float32.
// ROUND 7 = round 6 + ABLATION: a STORES=0 twin of k_edge runs first (oute
// stores compiled out, all else identical & live via nm2/cd2 dependency),
// then the real k_edge overwrites everything -> output still correct.
// bench dur_us = baseline(~101us) + D1(nostore k_edge). Decisive fork:
// D1 ~ 95us => stores irrelevant; D1 ~ 40us => write path is the limiter.

typedef unsigned short ushort_t;
typedef __attribute__((ext_vector_type(8))) short short8;
typedef __attribute__((ext_vector_type(4))) float f32x4;

__device__ __forceinline__ ushort_t f2bf(float f) {
  unsigned int x = __builtin_bit_cast(unsigned int, f);
  x += 0x7fffu + ((x >> 16) & 1u);
  return (ushort_t)(x >> 16);
}
__device__ __forceinline__ float bf2f(ushort_t u) {
  unsigned int x = ((unsigned int)u) << 16;
  return __builtin_bit_cast(float, x);
}

__global__ void k_sent777(float* out0) { out0[threadIdx.x] = 777.f; }

// ---------------- kernel 1: per-node pre-projections ----------------
__global__ __launch_bounds__(128)
void k_pre(const float* nf, const float* We1, const float* be1,
           const float* Wa, float* pre_i, float* pre_j, float* api, float* apj) {
  int r = blockIdx.x, t = threadIdx.x;
  __shared__ float nfv[128];
  __shared__ float red[4];
  nfv[t] = nf[(size_t)r * 128 + t];
  __syncthreads();
  float s1 = be1[t], s2 = 0.f;
  for (int c = 0; c < 128; ++c) {
    float x = nfv[c];
    s1 += x * We1[c * 128 + t];
    s2 += x * We1[(128 + c) * 128 + t];
  }
  pre_i[(size_t)r * 128 + t] = s1;
  pre_j[(size_t)r * 128 + t] = s2;
  float t1 = nfv[t] * Wa[t];
  float t2 = nfv[t] * Wa[128 + t];
#pragma unroll
  for (int o = 32; o > 0; o >>= 1) { t1 += __shfl_down(t1, o); t2 += __shfl_down(t2, o); }
  if ((t & 63) == 0) { red[(t >> 6) * 2] = t1; red[(t >> 6) * 2 + 1] = t2; }
  __syncthreads();
  if (t == 0) { api[r] = red[0] + red[2]; apj[r] = red[1] + red[3]; }
}

// ---------------- kernel 2: pack We2 (fp32) into bf16 MFMA A^T-fragments ----
__global__ __launch_bounds__(256)
void k_pack(const float* We2, ushort_t* bpack) {
  int t = blockIdx.x * 256 + threadIdx.x;
  if (t >= 2048) return;
  int ks = t >> 9, mt = (t >> 6) & 7, l = t & 63;
  int kb = ks * 32 + (l >> 4) * 8, col = mt * 16 + (l & 15);
#pragma unroll
  for (int e = 0; e < 8; ++e) bpack[t * 8 + e] = f2bf(We2[(kb + e) * 128 + col]);
}

// ---------------- kernel 3: edge MLP + attention + reductions ----------------
// Template STORES: 1 = real (writes oute), 0 = diagnostic twin (no oute
// stores; everything else identical; compute kept live through nm2/cd2).
template <int STORES>
__global__ __launch_bounds__(512, 2)
void k_edge_t(const float* co, const float* efo, const float* mk,
              const float* We1, const float* be2, const float* Wa, const float* ba,
              const float* lnes, const float* lneb, const int* eidx,
              const float* pre_i, const float* pre_j, const float* api, const float* apj,
              const ushort_t* bpack, float* oute, float* nm2, float* cd2) {
  __shared__ __align__(16) ushort_t A_lds[8 * 64 * 8];   // 8KB, frag-order [mt][lane][e]
  __shared__ __align__(16) ushort_t h1s[128 * 136];      // 34.8KB bf16 h1 tile
  __shared__ float2 mrsv[128];                           // per-row {mean, rsv}
  __shared__ float attw[128];
  __shared__ float nmp[8][128];
  __shared__ float cred[2][3];

  const int bx = blockIdx.x;
  const int r = bx >> 1, half = bx & 1;
  const int b = r >> 8;
  const int t = threadIdx.x;          // 0..511
  const int lane = t & 63, w = t >> 6;
  const int s4 = lane >> 4;           // 0..3 (k-slice / row-quad selector)
  const int chan = w * 16 + (lane & 15);
  const int gbase = b * 256 + half * 128;

  // ---- per-lane W fragment (K=32: rows 0..15=Wef, 16=wd2, 17..31=0) ----
  short8 wfrag;
#pragma unroll
  for (int e = 0; e < 8; ++e) {
    int k = s4 * 8 + e;
    float wv = 0.f;
    if (k < 16) wv = We1[(257 + k) * 128 + chan];
    else if (k == 16) wv = We1[256 * 128 + chan];
    wfrag[e] = (short)f2bf(wv);
  }
  const float preIc = pre_i[(size_t)r * 128 + chan];
  const float lnsc = lnes[chan], lnbc = lneb[chan];

  // ---- A-tile staging (frag order): thread t -> (mt=t>>6, l=t&63) ----
  {
    const int mt = t >> 6, l = t & 63, sl = l >> 4, row = mt * 16 + (l & 15);
    short8* dst = reinterpret_cast<short8*>(A_lds + ((size_t)(mt * 64 + l)) * 8);
    if (sl < 2) {
      const float* efp = efo + ((size_t)(r * 256 + half * 128 + row)) * 16 + sl * 8;
      f32x4 e0 = *reinterpret_cast<const f32x4*>(efp);
      f32x4 e1 = *reinterpret_cast<const f32x4*>(efp + 4);
      short8 pk;
#pragma unroll
      for (int x = 0; x < 4; ++x) { pk[x] = (short)f2bf(e0[x]); pk[4 + x] = (short)f2bf(e1[x]); }
      *dst = pk;
    } else if (sl == 3) {
      *dst = (short8){0, 0, 0, 0, 0, 0, 0, 0};
    }
    // sl==2 written by attention pass (d2)
  }

  // ---- attention + d2 + coord-dir (threads 0..127, one per edge row) ----
  if (t < 128) {
    const int j = half * 128 + t;
    const int gj = b * 256 + j;
    float dx = co[r * 3 + 0] - co[gj * 3 + 0];
    float dy = co[r * 3 + 1] - co[gj * 3 + 1];
    float dz = co[r * 3 + 2] - co[gj * 3 + 2];
    float d2 = dx * dx + dy * dy + dz * dz;

    float a = api[r] + apj[gj] + ba[0] + d2 * Wa[256];
    const float* efp = efo + ((size_t)r * 256 + j) * 16;
    f32x4 e0 = *reinterpret_cast<const f32x4*>(efp);
    f32x4 e1 = *reinterpret_cast<const f32x4*>(efp + 4);
    f32x4 e2 = *reinterpret_cast<const f32x4*>(efp + 8);
    f32x4 e3 = *reinterpret_cast<const f32x4*>(efp + 12);
#pragma unroll
    for (int x = 0; x < 4; ++x) {
      a += e0[x] * Wa[257 + x] + e1[x] * Wa[261 + x]
         + e2[x] * Wa[265 + x] + e3[x] * Wa[269 + x];
    }
    float att = 1.f / (1.f + __expf(-a));
    float aw = att * (float)eidx[(size_t)r * 256 + j];
    attw[t] = aw * mk[r] * mk[gj];

    short8 dz8 = (short8){0, 0, 0, 0, 0, 0, 0, 0};
    dz8[0] = (short)f2bf(d2);
    *reinterpret_cast<short8*>(A_lds + ((size_t)((t >> 4) * 64 + 32 + (t & 15))) * 8) = dz8;

    float invn = rsqrtf(d2 + 1e-8f);
    float c0 = dx * invn * aw, c1 = dy * invn * aw, c2 = dz * invn * aw;
#pragma unroll
    for (int o = 32; o > 0; o >>= 1) {
      c0 += __shfl_down(c0, o); c1 += __shfl_down(c1, o); c2 += __shfl_down(c2, o);
    }
    if (lane == 0) { cred[w][0] = c0; cred[w][1] = c1; cred[w][2] = c2; }
  }
  __syncthreads();

  // ---- phase 1 MFMA: D1[mt] = A_frag[mt] x wfrag; add pre terms ----
  f32x4 acc1[8];
#pragma unroll
  for (int mt = 0; mt < 8; ++mt) {
    short8 afr = *reinterpret_cast<const short8*>(A_lds + ((size_t)(mt * 64 + lane)) * 8);
    acc1[mt] = __builtin_amdgcn_mfma_f32_16x16x32_bf16(
        afr, wfrag, (f32x4){0.f, 0.f, 0.f, 0.f}, 0, 0, 0);
  }
#pragma unroll
  for (int mt = 0; mt < 8; ++mt) {
#pragma unroll
    for (int reg = 0; reg < 4; ++reg) {
      int row = mt * 16 + s4 * 4 + reg;
      float v = acc1[mt][reg] + preIc + pre_j[((size_t)(gbase + row)) * 128 + chan];
      acc1[mt][reg] = v;
      h1s[row * 136 + chan] = f2bf(v);
    }
  }
  __syncthreads();

  // ---- row LN stats (one owner thread per row, fixed-order serial sum) ----
  if (t < 128) {
    const short8* hr8 = reinterpret_cast<const short8*>(h1s + t * 136);
    float sum = 0.f, ss = 0.f;
#pragma unroll
    for (int q = 0; q < 16; ++q) {
      short8 pk = hr8[q];
#pragma unroll
      for (int x = 0; x < 8; ++x) {
        float f = bf2f((ushort_t)pk[x]);
        sum += f; ss += f * f;
      }
    }
    float mean = sum * (1.f / 128.f);
    float var = fmaxf(ss * (1.f / 128.f) - mean * mean, 0.f);
    mrsv[t] = make_float2(mean, rsqrtf(var + 1e-6f));
  }
  __syncthreads();

  // ---- apply LN + ReLU, write final h1 (bf16) ----
#pragma unroll
  for (int mt = 0; mt < 8; ++mt) {
#pragma unroll
    for (int reg = 0; reg < 4; ++reg) {
      int row = mt * 16 + s4 * 4 + reg;
      float2 mr = mrsv[row];
      float gv = (acc1[mt][reg] - mr.x) * mr.y * lnsc + lnbc;
      h1s[row * 136 + chan] = f2bf(fmaxf(gv, 0.f));
    }
  }
  __syncthreads();

  if (t == 0) {
#pragma unroll
    for (int d = 0; d < 3; ++d)
      cd2[(size_t)(half * 1024 + r) * 3 + d] = cred[0][d] + cred[1][d];
  }

  // ---- phase 2: EM^T tiles = We2^T (A) x H1^T (B) ----
  f32x4 acc[8];
#pragma unroll
  for (int mt = 0; mt < 8; ++mt) acc[mt] = (f32x4){0.f, 0.f, 0.f, 0.f};

  const short* h1p = reinterpret_cast<const short*>(h1s);
  const int nrow = w * 16 + (lane & 15);
#pragma unroll
  for (int ks = 0; ks < 4; ++ks) {
    short8 hfr = *reinterpret_cast<const short8*>(
        h1p + nrow * 136 + ks * 32 + (s4 * 8));
#pragma unroll
    for (int mt = 0; mt < 8; ++mt) {
      short8 afr = *reinterpret_cast<const short8*>(bpack + (((ks * 8 + mt) * 64 + lane) * 8));
      acc[mt] = __builtin_amdgcn_mfma_f32_16x16x32_bf16(afr, hfr, acc[mt], 0, 0, 0);
    }
  }

  const size_t obase = ((size_t)r * 256 + half * 128) * 128;
  const float wgt = attw[nrow];
  const int mq = s4 * 4;
  float pm[8][4];
#pragma unroll
  for (int mt = 0; mt < 8; ++mt) {
    f32x4 b4 = *reinterpret_cast<const f32x4*>(be2 + mt * 16 + mq);
    f32x4 val = acc[mt] + b4;
    if constexpr (STORES) {
      *reinterpret_cast<f32x4*>(oute + obase + (size_t)nrow * 128 + mt * 16 + mq) = val;
    }
#pragma unroll
    for (int x = 0; x < 4; ++x) pm[mt][x] = val[x] * wgt;
  }
#pragma unroll
  for (int mt = 0; mt < 8; ++mt)
#pragma unroll
    for (int x = 0; x < 4; ++x) {
      float v = pm[mt][x];
      v += __shfl_xor(v, 1); v += __shfl_xor(v, 2);
      v += __shfl_xor(v, 4); v += __shfl_xor(v, 8);
      pm[mt][x] = v;
    }
  if ((lane & 15) == 0) {
#pragma unroll
    for (int mt = 0; mt < 8; ++mt)
#pragma unroll
      for (int x = 0; x < 4; ++x) nmp[w][mt * 16 + mq + x] = pm[mt][x];
  }
  __syncthreads();
  if (t < 128) {
    float acc8 = nmp[0][t] + nmp[1][t] + nmp[2][t] + nmp[3][t]
               + nmp[4][t] + nmp[5][t] + nmp[6][t] + nmp[7][t];
    nm2[(size_t)(half * 1024 + r) * 128 + t] = acc8;
  }
}

// ---------------- kernel 4: node MLP + coord MLP + outputs ----------------
__device__ __forceinline__ float bsum128(float v, float* red, int t) {
#pragma unroll
  for (int o = 32; o > 0; o >>= 1) v += __shfl_down(v, o);
  __syncthreads();
  if ((t & 63) == 0) red[t >> 6] = v;
  __syncthreads();
  return red[0] + red[1];
}

__global__ __launch_bounds__(128)
void k_node(const float* nf, const float* co, const float* mk,
            const float* Wn1, const float* bn1, const float* lnns, const float* lnnb,
            const float* Wn2, const float* bn2,
            const float* Wc1, const float* bc1, const float* lncs, const float* lncb,
            const float* Wc2, const float* bc2,
            const float* nm2, const float* cd2,
            float* out0, float* out1) {
  int r = blockIdx.x, t = threadIdx.x;
  __shared__ float nin[256];
  __shared__ float hf[128];
  __shared__ float red[2];
  float nfv = nf[(size_t)r * 128 + t];
  float nmv = nm2[(size_t)r * 128 + t] + nm2[(size_t)(1024 + r) * 128 + t];
  nin[t] = nfv; nin[128 + t] = nmv;
  __syncthreads();
  float s1 = bn1[t];
  for (int c = 0; c < 256; ++c) s1 += nin[c] * Wn1[c * 128 + t];
  float mean = bsum128(s1, red, t) * (1.f / 128.f);
  float var = fmaxf(bsum128(s1 * s1, red, t) * (1.f / 128.f) - mean * mean, 0.f);
  float hv = (s1 - mean) * rsqrtf(var + 1e-6f) * lnns[t] + lnnb[t];
  hv = fmaxf(hv, 0.f);
  hf[t] = hv;
  __syncthreads();
  float o1 = bn2[t] + nfv;  // residual
  for (int c = 0; c < 128; ++c) o1 += hf[c] * Wn2[c * 128 + t];
  out0[(size_t)r * 128 + t] = o1;
  float g = bc1[t];
  for (int c = 0; c < 128; ++c) g += nin[128 + c] * Wc1[c * 128 + t];
  float gm = bsum128(g, red, t) * (1.f / 128.f);
  float gv = fmaxf(bsum128(g * g, red, t) * (1.f / 128.f) - gm * gm, 0.f);
  float gh = fmaxf((g - gm) * rsqrtf(gv + 1e-6f) * lncs[t] + lncb[t], 0.f);
  float cm = bsum128(gh * Wc2[t], red, t) + bc2[0];
  if (t < 3) {
    float cd = cd2[(size_t)r * 3 + t] + cd2[(size_t)(1024 + r) * 3 + t];
    float nc = co[(size_t)r * 3 + t] + cd * cm * mk[r];
    out1[(size_t)r * 3 + t] = nc;
  }
}

extern "C" void kernel_launch(void* const* d_in, const int* in_sizes, int n_in,
                              void* d_out, int out_size, void* d_ws, size_t ws_size,
                              hipStream_t stream) {
  const float* nf   = (const float*)d_in[0];
  const float* co   = (const float*)d_in[1];
  const float* efo  = (const float*)d_in[2];
  const float* mk   = (const float*)d_in[3];
  const float* We1  = (const float*)d_in[4];
  const float* be1  = (const float*)d_in[5];
  const float* lnes = (const float*)d_in[6];
  const float* lneb = (const float*)d_in[7];
  const float* We2  = (const float*)d_in[8];
  const float* be2  = (const float*)d_in[9];
  const float* Wa   = (const float*)d_in[10];
  const float* ba   = (const float*)d_in[11];
  const float* Wn1  = (const float*)d_in[12];
  const float* bn1  = (const float*)d_in[13];
  const float* lnns = (const float*)d_in[14];
  const float* lnnb = (const float*)d_in[15];
  const float* Wn2  = (const float*)d_in[16];
  const float* bn2  = (const float*)d_in[17];
  const float* Wc1  = (const float*)d_in[18];
  const float* bc1  = (const float*)d_in[19];
  const float* lncs = (const float*)d_in[20];
  const float* lncb = (const float*)d_in[21];
  const float* Wc2  = (const float*)d_in[22];
  const float* bc2  = (const float*)d_in[23];
  const int* eidx   = (const int*)d_in[24];

  float* out0 = (float*)d_out;        // new_node_features [4,256,128]
  float* out1 = out0 + 131072;        // new_coordinates  [4,256,3]
  float* oute = out1 + 3072;          // new_edge_features [4,256,256,128]

  const size_t need = (size_t)(131072 + 131072 + 1024 + 1024 + 262144 + 6144) * 4 + 16384 * 2;
  if (ws_size < need) {
    k_sent777<<<1, 128, 0, stream>>>(out0);
    return;
  }
  float* ws    = (float*)d_ws;
  float* pre_i = ws;
  float* pre_j = pre_i + 131072;
  float* api   = pre_j + 131072;
  float* apj   = api + 1024;
  float* nm2   = apj + 1024;
  float* cd2   = nm2 + 262144;
  ushort_t* bpack = (ushort_t*)(cd2 + 6144);

  k_pre<<<1024, 128, 0, stream>>>(nf, We1, be1, Wa, pre_i, pre_j, api, apj);
  k_pack<<<8, 256, 0, stream>>>(We2, bpack);
  // DIAGNOSTIC: no-store twin first (its nm2/cd2 writes are overwritten below)
  k_edge_t<0><<<2048, 512, 0, stream>>>(co, efo, mk, We1, be2, Wa, ba, lnes, lneb, eidx,
                                        pre_i, pre_j, api, apj, bpack, oute, nm2, cd2);
  // REAL kernel (authoritative outputs)
  k_edge_t<1><<<2048, 512, 0, stream>>>(co, efo, mk, We1, be2, Wa, ba, lnes, lneb, eidx,
                                        pre_i, pre_j, api, apj, bpack, oute, nm2, cd2);
  k_node<<<1024, 128, 0, stream>>>(nf, co, mk, Wn1, bn1, lnns, lnnb, Wn2, bn2,
                                   Wc1, bc1, lncs, lncb, Wc2, bc2, nm2, cd2, out0, out1);
}

// Round 8
// 115.054 us; speedup vs baseline: 1.3777x; 1.3777x over previous
//
#include <hip/hip_runtime.h>
#include <hip/hip_bf16.h>

// EGNN layer, MI355X. B=4, N=256, H=128, E=16, EIN=273. All I/O float32.
// Phase 1 TRANSPOSED: h1^T = Wx^T x [ef|d2|pad]^T  (one lane = one edge row,
// 32 chans in-register) -> coalesced f32x4 pre_i/pre_j adds, in-register LN
// (shfl_xor), attention fused into the same lanes (wgt stays in-register),
// no A-staging LDS, 2 barriers total. Phase 2 unchanged (EM^T = We2^T x H1^T,
// coalesced f32x4 stores). Deterministic fixed-order reductions only.

typedef unsigned short ushort_t;
typedef __attribute__((ext_vector_type(8))) short short8;
typedef __attribute__((ext_vector_type(4))) short short4_t;
typedef __attribute__((ext_vector_type(4))) float f32x4;

__device__ __forceinline__ ushort_t f2bf(float f) {
  unsigned int x = __builtin_bit_cast(unsigned int, f);
  x += 0x7fffu + ((x >> 16) & 1u);
  return (ushort_t)(x >> 16);
}

__global__ void k_sent777(float* out0) { out0[threadIdx.x] = 777.f; }

// ---------------- kernel 1: per-node pre-projections ----------------
__global__ __launch_bounds__(128)
void k_pre(const float* nf, const float* We1, const float* be1,
           const float* Wa, float* pre_i, float* pre_j, float* api, float* apj) {
  int r = blockIdx.x, t = threadIdx.x;
  __shared__ float nfv[128];
  __shared__ float red[4];
  nfv[t] = nf[(size_t)r * 128 + t];
  __syncthreads();
  float s1 = be1[t], s2 = 0.f;
  for (int c = 0; c < 128; ++c) {
    float x = nfv[c];
    s1 += x * We1[c * 128 + t];
    s2 += x * We1[(128 + c) * 128 + t];
  }
  pre_i[(size_t)r * 128 + t] = s1;
  pre_j[(size_t)r * 128 + t] = s2;
  float t1 = nfv[t] * Wa[t];
  float t2 = nfv[t] * Wa[128 + t];
#pragma unroll
  for (int o = 32; o > 0; o >>= 1) { t1 += __shfl_down(t1, o); t2 += __shfl_down(t2, o); }
  if ((t & 63) == 0) { red[(t >> 6) * 2] = t1; red[(t >> 6) * 2 + 1] = t2; }
  __syncthreads();
  if (t == 0) { api[r] = red[0] + red[2]; apj[r] = red[1] + red[3]; }
}

// ---------------- kernel 2: pack We2 (bpack) and Wx^T (wpack) ----------------
// bpack[((ks*8+mt)*64+l)*8+e] = bf16(We2[ks*32+(l>>4)*8+e][mt*16+(l&15)])
// wpack[(mt*64+l)*8+e]        = bf16(Wx^T[mt*16+(l&15)][(l>>4)*8+e])
//   Wx^T[chan][k] : k<16 -> We1[(257+k)*128+chan]; k==16 -> We1[256*128+chan]; else 0
__global__ __launch_bounds__(256)
void k_pack(const float* We2, const float* We1, ushort_t* bpack, ushort_t* wpack) {
  int t = blockIdx.x * 256 + threadIdx.x;
  if (t < 2048) {
    int ks = t >> 9, mt = (t >> 6) & 7, l = t & 63;
    int kb = ks * 32 + (l >> 4) * 8, col = mt * 16 + (l & 15);
#pragma unroll
    for (int e = 0; e < 8; ++e) bpack[t * 8 + e] = f2bf(We2[(kb + e) * 128 + col]);
  } else if (t < 2560) {
    int q = t - 2048;
    int mt = q >> 6, l = q & 63;
    int chan = mt * 16 + (l & 15), kb = (l >> 4) * 8;
#pragma unroll
    for (int e = 0; e < 8; ++e) {
      int k = kb + e;
      float wv = 0.f;
      if (k < 16) wv = We1[(257 + k) * 128 + chan];
      else if (k == 16) wv = We1[256 * 128 + chan];
      wpack[q * 8 + e] = f2bf(wv);
    }
  }
}

// ---------------- kernel 3: edge MLP + attention + reductions ----------------
// grid 2048: block = (r = b*256+i, half of j). 512 threads = 8 waves.
// Lane identity (both phases): row = w*16 + (lane&15); s4 = lane>>4.
__global__ __launch_bounds__(512, 8)
void k_edge(const float* co, const float* efo, const float* mk,
            const float* be2, const float* Wa, const float* ba,
            const float* lnes, const float* lneb, const int* eidx,
            const float* pre_i, const float* pre_j, const float* api, const float* apj,
            const ushort_t* bpack, const ushort_t* wpack,
            float* oute, float* nm2, float* cd2) {
  __shared__ __align__(16) ushort_t h1s[128 * 136];  // 34.8KB bf16 h1 tile
  __shared__ float nmp[8][128];
  __shared__ float cred[8][3];

  const int bx = blockIdx.x;
  const int r = bx >> 1, half = bx & 1;
  const int b = r >> 8;
  const int t = threadIdx.x;          // 0..511
  const int lane = t & 63, w = t >> 6;
  const int s4 = lane >> 4, li = lane & 15;
  const int row = w * 16 + li;        // edge row in tile (0..127)
  const int j = half * 128 + row;
  const int gj = b * 256 + j;

  // ---- coords / d2 (all lanes, own row) ----
  float dx = co[r * 3 + 0] - co[gj * 3 + 0];
  float dy = co[r * 3 + 1] - co[gj * 3 + 1];
  float dz = co[r * 3 + 2] - co[gj * 3 + 2];
  float d2 = dx * dx + dy * dy + dz * dz;

  // ---- B-frag ([ef|d2|pad]^T) + attention partial dot ----
  short8 bfr = (short8){0, 0, 0, 0, 0, 0, 0, 0};
  float dot = 0.f;
  if (s4 < 2) {
    const float* efp = efo + ((size_t)r * 256 + j) * 16 + s4 * 8;
    f32x4 a0 = *reinterpret_cast<const f32x4*>(efp);
    f32x4 a1 = *reinterpret_cast<const f32x4*>(efp + 4);
#pragma unroll
    for (int x = 0; x < 4; ++x) { bfr[x] = (short)f2bf(a0[x]); bfr[4 + x] = (short)f2bf(a1[x]); }
    const float* wap = Wa + 257 + s4 * 8;
#pragma unroll
    for (int x = 0; x < 4; ++x) dot += a0[x] * wap[x] + a1[x] * wap[4 + x];
  } else if (s4 == 2) {
    bfr[0] = (short)f2bf(d2);
    dot = api[r] + apj[gj] + ba[0] + d2 * Wa[256];
  }
  dot += __shfl_xor(dot, 16);
  dot += __shfl_xor(dot, 32);
  float att = 1.f / (1.f + __expf(-dot));
  float aw = att * (float)eidx[(size_t)r * 256 + j];
  const float wgt = aw * mk[r] * mk[gj];

  // ---- coord-dir reduction (count each row once via s4==0) ----
  {
    float invn = rsqrtf(d2 + 1e-8f);
    float c0 = (s4 == 0) ? dx * invn * aw : 0.f;
    float c1 = (s4 == 0) ? dy * invn * aw : 0.f;
    float c2 = (s4 == 0) ? dz * invn * aw : 0.f;
#pragma unroll
    for (int o = 1; o < 64; o <<= 1) {
      c0 += __shfl_xor(c0, o); c1 += __shfl_xor(c1, o); c2 += __shfl_xor(c2, o);
    }
    if (lane == 0) { cred[w][0] = c0; cred[w][1] = c1; cred[w][2] = c2; }
  }

  // ---- phase 1 MFMA: acc1[mt] = h1^T tile (lane: row fixed, chans mt*16+s4*4..) ----
  f32x4 acc1[8];
#pragma unroll
  for (int mt = 0; mt < 8; ++mt) {
    short8 wfr = *reinterpret_cast<const short8*>(wpack + ((size_t)(mt * 64 + lane)) * 8);
    acc1[mt] = __builtin_amdgcn_mfma_f32_16x16x32_bf16(
        wfr, bfr, (f32x4){0.f, 0.f, 0.f, 0.f}, 0, 0, 0);
  }

  // ---- add pre_i + pre_j (coalesced f32x4), in-register LN stats ----
  const float* pir = pre_i + (size_t)r * 128;
  const float* pjr = pre_j + (size_t)gj * 128;
  float s = 0.f, ss = 0.f;
#pragma unroll
  for (int mt = 0; mt < 8; ++mt) {
    const int c0i = mt * 16 + s4 * 4;
    f32x4 pj = *reinterpret_cast<const f32x4*>(pjr + c0i);
    f32x4 pi = *reinterpret_cast<const f32x4*>(pir + c0i);
    acc1[mt] += pi + pj;
#pragma unroll
    for (int x = 0; x < 4; ++x) { s += acc1[mt][x]; ss += acc1[mt][x] * acc1[mt][x]; }
  }
  s += __shfl_xor(s, 16);  s += __shfl_xor(s, 32);
  ss += __shfl_xor(ss, 16); ss += __shfl_xor(ss, 32);
  const float mean = s * (1.f / 128.f);
  const float var = fmaxf(ss * (1.f / 128.f) - mean * mean, 0.f);
  const float rsv = rsqrtf(var + 1e-6f);

  // ---- apply LN + ReLU, write h1 (bf16) once ----
  ushort_t* hrow = h1s + row * 136;
#pragma unroll
  for (int mt = 0; mt < 8; ++mt) {
    const int c0i = mt * 16 + s4 * 4;
    f32x4 ln4 = *reinterpret_cast<const f32x4*>(lnes + c0i);
    f32x4 lb4 = *reinterpret_cast<const f32x4*>(lneb + c0i);
    short4_t pk;
#pragma unroll
    for (int x = 0; x < 4; ++x) {
      float gv = (acc1[mt][x] - mean) * rsv * ln4[x] + lb4[x];
      pk[x] = (short)f2bf(fmaxf(gv, 0.f));
    }
    *reinterpret_cast<short4_t*>(hrow + c0i) = pk;
  }
  __syncthreads();

  if (t == 0) {
#pragma unroll
    for (int d = 0; d < 3; ++d)
      cd2[(size_t)(half * 1024 + r) * 3 + d] =
          ((cred[0][d] + cred[1][d]) + (cred[2][d] + cred[3][d]))
        + ((cred[4][d] + cred[5][d]) + (cred[6][d] + cred[7][d]));
  }

  // ---- phase 2: EM^T tiles = We2^T (A) x H1^T (B); coalesced f32x4 stores ----
  f32x4 acc[8];
#pragma unroll
  for (int mt = 0; mt < 8; ++mt) acc[mt] = (f32x4){0.f, 0.f, 0.f, 0.f};

  const short* h1p = reinterpret_cast<const short*>(h1s);
#pragma unroll
  for (int ks = 0; ks < 4; ++ks) {
    short8 hfr = *reinterpret_cast<const short8*>(h1p + row * 136 + ks * 32 + s4 * 8);
#pragma unroll
    for (int mt = 0; mt < 8; ++mt) {
      short8 afr = *reinterpret_cast<const short8*>(bpack + (((ks * 8 + mt) * 64 + lane) * 8));
      acc[mt] = __builtin_amdgcn_mfma_f32_16x16x32_bf16(afr, hfr, acc[mt], 0, 0, 0);
    }
  }

  const size_t obase = ((size_t)r * 256 + half * 128) * 128;
  const int mq = s4 * 4;
  float pm[8][4];
#pragma unroll
  for (int mt = 0; mt < 8; ++mt) {
    f32x4 b4 = *reinterpret_cast<const f32x4*>(be2 + mt * 16 + mq);
    f32x4 val = acc[mt] + b4;
    *reinterpret_cast<f32x4*>(oute + obase + (size_t)row * 128 + mt * 16 + mq) = val;
#pragma unroll
    for (int x = 0; x < 4; ++x) pm[mt][x] = val[x] * wgt;
  }
#pragma unroll
  for (int mt = 0; mt < 8; ++mt)
#pragma unroll
    for (int x = 0; x < 4; ++x) {
      float v = pm[mt][x];
      v += __shfl_xor(v, 1); v += __shfl_xor(v, 2);
      v += __shfl_xor(v, 4); v += __shfl_xor(v, 8);
      pm[mt][x] = v;
    }
  if (li == 0) {
#pragma unroll
    for (int mt = 0; mt < 8; ++mt)
#pragma unroll
      for (int x = 0; x < 4; ++x) nmp[w][mt * 16 + mq + x] = pm[mt][x];
  }
  __syncthreads();
  if (t < 128) {
    float acc8 = ((nmp[0][t] + nmp[1][t]) + (nmp[2][t] + nmp[3][t]))
               + ((nmp[4][t] + nmp[5][t]) + (nmp[6][t] + nmp[7][t]));
    nm2[(size_t)(half * 1024 + r) * 128 + t] = acc8;
  }
}

// ---------------- kernel 4: node MLP + coord MLP + outputs ----------------
__device__ __forceinline__ float bsum128(float v, float* red, int t) {
#pragma unroll
  for (int o = 32; o > 0; o >>= 1) v += __shfl_down(v, o);
  __syncthreads();
  if ((t & 63) == 0) red[t >> 6] = v;
  __syncthreads();
  return red[0] + red[1];
}

__global__ __launch_bounds__(128)
void k_node(const float* nf, const float* co, const float* mk,
            const float* Wn1, const float* bn1, const float* lnns, const float* lnnb,
            const float* Wn2, const float* bn2,
            const float* Wc1, const float* bc1, const float* lncs, const float* lncb,
            const float* Wc2, const float* bc2,
            const float* nm2, const float* cd2,
            float* out0, float* out1) {
  int r = blockIdx.x, t = threadIdx.x;
  __shared__ float nin[256];
  __shared__ float hf[128];
  __shared__ float red[2];
  float nfv = nf[(size_t)r * 128 + t];
  float nmv = nm2[(size_t)r * 128 + t] + nm2[(size_t)(1024 + r) * 128 + t];
  nin[t] = nfv; nin[128 + t] = nmv;
  __syncthreads();
  float s1 = bn1[t];
  for (int c = 0; c < 256; ++c) s1 += nin[c] * Wn1[c * 128 + t];
  float mean = bsum128(s1, red, t) * (1.f / 128.f);
  float var = fmaxf(bsum128(s1 * s1, red, t) * (1.f / 128.f) - mean * mean, 0.f);
  float hv = (s1 - mean) * rsqrtf(var + 1e-6f) * lnns[t] + lnnb[t];
  hv = fmaxf(hv, 0.f);
  hf[t] = hv;
  __syncthreads();
  float o1 = bn2[t] + nfv;  // residual
  for (int c = 0; c < 128; ++c) o1 += hf[c] * Wn2[c * 128 + t];
  out0[(size_t)r * 128 + t] = o1;
  float g = bc1[t];
  for (int c = 0; c < 128; ++c) g += nin[128 + c] * Wc1[c * 128 + t];
  float gm = bsum128(g, red, t) * (1.f / 128.f);
  float gv = fmaxf(bsum128(g * g, red, t) * (1.f / 128.f) - gm * gm, 0.f);
  float gh = fmaxf((g - gm) * rsqrtf(gv + 1e-6f) * lncs[t] + lncb[t], 0.f);
  float cm = bsum128(gh * Wc2[t], red, t) + bc2[0];
  if (t < 3) {
    float cd = cd2[(size_t)r * 3 + t] + cd2[(size_t)(1024 + r) * 3 + t];
    float nc = co[(size_t)r * 3 + t] + cd * cm * mk[r];
    out1[(size_t)r * 3 + t] = nc;
  }
}

extern "C" void kernel_launch(void* const* d_in, const int* in_sizes, int n_in,
                              void* d_out, int out_size, void* d_ws, size_t ws_size,
                              hipStream_t stream) {
  const float* nf   = (const float*)d_in[0];
  const float* co   = (const float*)d_in[1];
  const float* efo  = (const float*)d_in[2];
  const float* mk   = (const float*)d_in[3];
  const float* We1  = (const float*)d_in[4];
  const float* be1  = (const float*)d_in[5];
  const float* lnes = (const float*)d_in[6];
  const float* lneb = (const float*)d_in[7];
  const float* We2  = (const float*)d_in[8];
  const float* be2  = (const float*)d_in[9];
  const float* Wa   = (const float*)d_in[10];
  const float* ba   = (const float*)d_in[11];
  const float* Wn1  = (const float*)d_in[12];
  const float* bn1  = (const float*)d_in[13];
  const float* lnns = (const float*)d_in[14];
  const float* lnnb = (const float*)d_in[15];
  const float* Wn2  = (const float*)d_in[16];
  const float* bn2  = (const float*)d_in[17];
  const float* Wc1  = (const float*)d_in[18];
  const float* bc1  = (const float*)d_in[19];
  const float* lncs = (const float*)d_in[20];
  const float* lncb = (const float*)d_in[21];
  const float* Wc2  = (const float*)d_in[22];
  const float* bc2  = (const float*)d_in[23];
  const int* eidx   = (const int*)d_in[24];

  float* out0 = (float*)d_out;        // new_node_features [4,256,128]
  float* out1 = out0 + 131072;        // new_coordinates  [4,256,3]
  float* oute = out1 + 3072;          // new_edge_features [4,256,256,128]

  // ws floats: pre_i | pre_j | api | apj | nm2 | cd2 | bpack(bf16) | wpack(bf16)
  const size_t need = (size_t)(131072 + 131072 + 1024 + 1024 + 262144 + 6144) * 4
                    + (16384 + 4096) * 2;
  if (ws_size < need) {
    k_sent777<<<1, 128, 0, stream>>>(out0);
    return;
  }
  float* ws    = (float*)d_ws;
  float* pre_i = ws;
  float* pre_j = pre_i + 131072;
  float* api   = pre_j + 131072;
  float* apj   = api + 1024;
  float* nm2   = apj + 1024;
  float* cd2   = nm2 + 262144;
  ushort_t* bpack = (ushort_t*)(cd2 + 6144);
  ushort_t* wpack = bpack + 16384;

  k_pre<<<1024, 128, 0, stream>>>(nf, We1, be1, Wa, pre_i, pre_j, api, apj);
  k_pack<<<10, 256, 0, stream>>>(We2, We1, bpack, wpack);
  k_edge<<<2048, 512, 0, stream>>>(co, efo, mk, be2, Wa, ba, lnes, lneb, eidx,
                                   pre_i, pre_j, api, apj, bpack, wpack,
                                   oute, nm2, cd2);
  k_node<<<1024, 128, 0, stream>>>(nf, co, mk, Wn1, bn1, lnns, lnnb, Wn2, bn2,
                                   Wc1, bc1, lncs, lncb, Wc2, bc2, nm2, cd2, out0, out1);
}

// Round 9
// 104.746 us; speedup vs baseline: 1.5133x; 1.0984x over previous
//
#include <hip/hip_runtime.h>
#include <hip/hip_bf16.h>

// EGNN layer, MI355X. B=4, N=256, H=128, E=16, EIN=273. All I/O float32.
// Phase 1 TRANSPOSED: h1^T = Wx^T x [ef|d2|pad]^T  (one lane = one edge row,
// 32 chans in-register) -> coalesced f32x4 pre_i/pre_j adds, in-register LN
// (shfl_xor), attention fused into the same lanes (wgt stays in-register),
// no A-staging LDS, 2 barriers total. Phase 2: EM^T = We2^T x H1^T, coalesced
// f32x4 stores. ROUND 9: launch_bounds (512,4) -- round 8's (512,8) forced a
// 32-VGPR cap and spilled (~64 live acc regs) => +68MB scratch writes.
// Deterministic fixed-order reductions only.

typedef unsigned short ushort_t;
typedef __attribute__((ext_vector_type(8))) short short8;
typedef __attribute__((ext_vector_type(4))) short short4_t;
typedef __attribute__((ext_vector_type(4))) float f32x4;

__device__ __forceinline__ ushort_t f2bf(float f) {
  unsigned int x = __builtin_bit_cast(unsigned int, f);
  x += 0x7fffu + ((x >> 16) & 1u);
  return (ushort_t)(x >> 16);
}

__global__ void k_sent777(float* out0) { out0[threadIdx.x] = 777.f; }

// ---------------- kernel 1: per-node pre-projections ----------------
__global__ __launch_bounds__(128)
void k_pre(const float* nf, const float* We1, const float* be1,
           const float* Wa, float* pre_i, float* pre_j, float* api, float* apj) {
  int r = blockIdx.x, t = threadIdx.x;
  __shared__ float nfv[128];
  __shared__ float red[4];
  nfv[t] = nf[(size_t)r * 128 + t];
  __syncthreads();
  float s1 = be1[t], s2 = 0.f;
  for (int c = 0; c < 128; ++c) {
    float x = nfv[c];
    s1 += x * We1[c * 128 + t];
    s2 += x * We1[(128 + c) * 128 + t];
  }
  pre_i[(size_t)r * 128 + t] = s1;
  pre_j[(size_t)r * 128 + t] = s2;
  float t1 = nfv[t] * Wa[t];
  float t2 = nfv[t] * Wa[128 + t];
#pragma unroll
  for (int o = 32; o > 0; o >>= 1) { t1 += __shfl_down(t1, o); t2 += __shfl_down(t2, o); }
  if ((t & 63) == 0) { red[(t >> 6) * 2] = t1; red[(t >> 6) * 2 + 1] = t2; }
  __syncthreads();
  if (t == 0) { api[r] = red[0] + red[2]; apj[r] = red[1] + red[3]; }
}

// ---------------- kernel 2: pack We2 (bpack) and Wx^T (wpack) ----------------
// bpack[((ks*8+mt)*64+l)*8+e] = bf16(We2[ks*32+(l>>4)*8+e][mt*16+(l&15)])
// wpack[(mt*64+l)*8+e]        = bf16(Wx^T[mt*16+(l&15)][(l>>4)*8+e])
//   Wx^T[chan][k] : k<16 -> We1[(257+k)*128+chan]; k==16 -> We1[256*128+chan]; else 0
__global__ __launch_bounds__(256)
void k_pack(const float* We2, const float* We1, ushort_t* bpack, ushort_t* wpack) {
  int t = blockIdx.x * 256 + threadIdx.x;
  if (t < 2048) {
    int ks = t >> 9, mt = (t >> 6) & 7, l = t & 63;
    int kb = ks * 32 + (l >> 4) * 8, col = mt * 16 + (l & 15);
#pragma unroll
    for (int e = 0; e < 8; ++e) bpack[t * 8 + e] = f2bf(We2[(kb + e) * 128 + col]);
  } else if (t < 2560) {
    int q = t - 2048;
    int mt = q >> 6, l = q & 63;
    int chan = mt * 16 + (l & 15), kb = (l >> 4) * 8;
#pragma unroll
    for (int e = 0; e < 8; ++e) {
      int k = kb + e;
      float wv = 0.f;
      if (k < 16) wv = We1[(257 + k) * 128 + chan];
      else if (k == 16) wv = We1[256 * 128 + chan];
      wpack[q * 8 + e] = f2bf(wv);
    }
  }
}

// ---------------- kernel 3: edge MLP + attention + reductions ----------------
// grid 2048: block = (r = b*256+i, half of j). 512 threads = 8 waves.
// Lane identity (both phases): row = w*16 + (lane&15); s4 = lane>>4.
__global__ __launch_bounds__(512, 4)
void k_edge(const float* co, const float* efo, const float* mk,
            const float* be2, const float* Wa, const float* ba,
            const float* lnes, const float* lneb, const int* eidx,
            const float* pre_i, const float* pre_j, const float* api, const float* apj,
            const ushort_t* bpack, const ushort_t* wpack,
            float* oute, float* nm2, float* cd2) {
  __shared__ __align__(16) ushort_t h1s[128 * 136];  // 34.8KB bf16 h1 tile
  __shared__ float nmp[8][128];
  __shared__ float cred[8][3];

  const int bx = blockIdx.x;
  const int r = bx >> 1, half = bx & 1;
  const int b = r >> 8;
  const int t = threadIdx.x;          // 0..511
  const int lane = t & 63, w = t >> 6;
  const int s4 = lane >> 4, li = lane & 15;
  const int row = w * 16 + li;        // edge row in tile (0..127)
  const int j = half * 128 + row;
  const int gj = b * 256 + j;

  // ---- coords / d2 (all lanes, own row) ----
  float dx = co[r * 3 + 0] - co[gj * 3 + 0];
  float dy = co[r * 3 + 1] - co[gj * 3 + 1];
  float dz = co[r * 3 + 2] - co[gj * 3 + 2];
  float d2 = dx * dx + dy * dy + dz * dz;

  // ---- B-frag ([ef|d2|pad]^T) + attention partial dot ----
  short8 bfr = (short8){0, 0, 0, 0, 0, 0, 0, 0};
  float dot = 0.f;
  if (s4 < 2) {
    const float* efp = efo + ((size_t)r * 256 + j) * 16 + s4 * 8;
    f32x4 a0 = *reinterpret_cast<const f32x4*>(efp);
    f32x4 a1 = *reinterpret_cast<const f32x4*>(efp + 4);
#pragma unroll
    for (int x = 0; x < 4; ++x) { bfr[x] = (short)f2bf(a0[x]); bfr[4 + x] = (short)f2bf(a1[x]); }
    const float* wap = Wa + 257 + s4 * 8;
#pragma unroll
    for (int x = 0; x < 4; ++x) dot += a0[x] * wap[x] + a1[x] * wap[4 + x];
  } else if (s4 == 2) {
    bfr[0] = (short)f2bf(d2);
    dot = api[r] + apj[gj] + ba[0] + d2 * Wa[256];
  }
  dot += __shfl_xor(dot, 16);
  dot += __shfl_xor(dot, 32);
  float att = 1.f / (1.f + __expf(-dot));
  float aw = att * (float)eidx[(size_t)r * 256 + j];
  const float wgt = aw * mk[r] * mk[gj];

  // ---- coord-dir reduction (count each row once via s4==0) ----
  {
    float invn = rsqrtf(d2 + 1e-8f);
    float c0 = (s4 == 0) ? dx * invn * aw : 0.f;
    float c1 = (s4 == 0) ? dy * invn * aw : 0.f;
    float c2 = (s4 == 0) ? dz * invn * aw : 0.f;
#pragma unroll
    for (int o = 1; o < 64; o <<= 1) {
      c0 += __shfl_xor(c0, o); c1 += __shfl_xor(c1, o); c2 += __shfl_xor(c2, o);
    }
    if (lane == 0) { cred[w][0] = c0; cred[w][1] = c1; cred[w][2] = c2; }
  }

  // ---- phase 1 MFMA: acc1[mt] = h1^T tile (lane: row fixed, chans mt*16+s4*4..) ----
  f32x4 acc1[8];
#pragma unroll
  for (int mt = 0; mt < 8; ++mt) {
    short8 wfr = *reinterpret_cast<const short8*>(wpack + ((size_t)(mt * 64 + lane)) * 8);
    acc1[mt] = __builtin_amdgcn_mfma_f32_16x16x32_bf16(
        wfr, bfr, (f32x4){0.f, 0.f, 0.f, 0.f}, 0, 0, 0);
  }

  // ---- add pre_i + pre_j (coalesced f32x4), in-register LN stats ----
  const float* pir = pre_i + (size_t)r * 128;
  const float* pjr = pre_j + (size_t)gj * 128;
  float s = 0.f, ss = 0.f;
#pragma unroll
  for (int mt = 0; mt < 8; ++mt) {
    const int c0i = mt * 16 + s4 * 4;
    f32x4 pj = *reinterpret_cast<const f32x4*>(pjr + c0i);
    f32x4 pi = *reinterpret_cast<const f32x4*>(pir + c0i);
    acc1[mt] += pi + pj;
#pragma unroll
    for (int x = 0; x < 4; ++x) { s += acc1[mt][x]; ss += acc1[mt][x] * acc1[mt][x]; }
  }
  s += __shfl_xor(s, 16);  s += __shfl_xor(s, 32);
  ss += __shfl_xor(ss, 16); ss += __shfl_xor(ss, 32);
  const float mean = s * (1.f / 128.f);
  const float var = fmaxf(ss * (1.f / 128.f) - mean * mean, 0.f);
  const float rsv = rsqrtf(var + 1e-6f);

  // ---- apply LN + ReLU, write h1 (bf16) once ----
  ushort_t* hrow = h1s + row * 136;
#pragma unroll
  for (int mt = 0; mt < 8; ++mt) {
    const int c0i = mt * 16 + s4 * 4;
    f32x4 ln4 = *reinterpret_cast<const f32x4*>(lnes + c0i);
    f32x4 lb4 = *reinterpret_cast<const f32x4*>(lneb + c0i);
    short4_t pk;
#pragma unroll
    for (int x = 0; x < 4; ++x) {
      float gv = (acc1[mt][x] - mean) * rsv * ln4[x] + lb4[x];
      pk[x] = (short)f2bf(fmaxf(gv, 0.f));
    }
    *reinterpret_cast<short4_t*>(hrow + c0i) = pk;
  }
  __syncthreads();

  if (t == 0) {
#pragma unroll
    for (int d = 0; d < 3; ++d)
      cd2[(size_t)(half * 1024 + r) * 3 + d] =
          ((cred[0][d] + cred[1][d]) + (cred[2][d] + cred[3][d]))
        + ((cred[4][d] + cred[5][d]) + (cred[6][d] + cred[7][d]));
  }

  // ---- phase 2: EM^T tiles = We2^T (A) x H1^T (B); coalesced f32x4 stores ----
  f32x4 acc[8];
#pragma unroll
  for (int mt = 0; mt < 8; ++mt) acc[mt] = (f32x4){0.f, 0.f, 0.f, 0.f};

  const short* h1p = reinterpret_cast<const short*>(h1s);
#pragma unroll
  for (int ks = 0; ks < 4; ++ks) {
    short8 hfr = *reinterpret_cast<const short8*>(h1p + row * 136 + ks * 32 + s4 * 8);
#pragma unroll
    for (int mt = 0; mt < 8; ++mt) {
      short8 afr = *reinterpret_cast<const short8*>(bpack + (((ks * 8 + mt) * 64 + lane) * 8));
      acc[mt] = __builtin_amdgcn_mfma_f32_16x16x32_bf16(afr, hfr, acc[mt], 0, 0, 0);
    }
  }

  const size_t obase = ((size_t)r * 256 + half * 128) * 128;
  const int mq = s4 * 4;
  float pm[8][4];
#pragma unroll
  for (int mt = 0; mt < 8; ++mt) {
    f32x4 b4 = *reinterpret_cast<const f32x4*>(be2 + mt * 16 + mq);
    f32x4 val = acc[mt] + b4;
    *reinterpret_cast<f32x4*>(oute + obase + (size_t)row * 128 + mt * 16 + mq) = val;
#pragma unroll
    for (int x = 0; x < 4; ++x) pm[mt][x] = val[x] * wgt;
  }
#pragma unroll
  for (int mt = 0; mt < 8; ++mt)
#pragma unroll
    for (int x = 0; x < 4; ++x) {
      float v = pm[mt][x];
      v += __shfl_xor(v, 1); v += __shfl_xor(v, 2);
      v += __shfl_xor(v, 4); v += __shfl_xor(v, 8);
      pm[mt][x] = v;
    }
  if (li == 0) {
#pragma unroll
    for (int mt = 0; mt < 8; ++mt)
#pragma unroll
      for (int x = 0; x < 4; ++x) nmp[w][mt * 16 + mq + x] = pm[mt][x];
  }
  __syncthreads();
  if (t < 128) {
    float acc8 = ((nmp[0][t] + nmp[1][t]) + (nmp[2][t] + nmp[3][t]))
               + ((nmp[4][t] + nmp[5][t]) + (nmp[6][t] + nmp[7][t]));
    nm2[(size_t)(half * 1024 + r) * 128 + t] = acc8;
  }
}

// ---------------- kernel 4: node MLP + coord MLP + outputs ----------------
__device__ __forceinline__ float bsum128(float v, float* red, int t) {
#pragma unroll
  for (int o = 32; o > 0; o >>= 1) v += __shfl_down(v, o);
  __syncthreads();
  if ((t & 63) == 0) red[t >> 6] = v;
  __syncthreads();
  return red[0] + red[1];
}

__global__ __launch_bounds__(128)
void k_node(const float* nf, const float* co, const float* mk,
            const float* Wn1, const float* bn1, const float* lnns, const float* lnnb,
            const float* Wn2, const float* bn2,
            const float* Wc1, const float* bc1, const float* lncs, const float* lncb,
            const float* Wc2, const float* bc2,
            const float* nm2, const float* cd2,
            float* out0, float* out1) {
  int r = blockIdx.x, t = threadIdx.x;
  __shared__ float nin[256];
  __shared__ float hf[128];
  __shared__ float red[2];
  float nfv = nf[(size_t)r * 128 + t];
  float nmv = nm2[(size_t)r * 128 + t] + nm2[(size_t)(1024 + r) * 128 + t];
  nin[t] = nfv; nin[128 + t] = nmv;
  __syncthreads();
  float s1 = bn1[t];
  for (int c = 0; c < 256; ++c) s1 += nin[c] * Wn1[c * 128 + t];
  float mean = bsum128(s1, red, t) * (1.f / 128.f);
  float var = fmaxf(bsum128(s1 * s1, red, t) * (1.f / 128.f) - mean * mean, 0.f);
  float hv = (s1 - mean) * rsqrtf(var + 1e-6f) * lnns[t] + lnnb[t];
  hv = fmaxf(hv, 0.f);
  hf[t] = hv;
  __syncthreads();
  float o1 = bn2[t] + nfv;  // residual
  for (int c = 0; c < 128; ++c) o1 += hf[c] * Wn2[c * 128 + t];
  out0[(size_t)r * 128 + t] = o1;
  float g = bc1[t];
  for (int c = 0; c < 128; ++c) g += nin[128 + c] * Wc1[c * 128 + t];
  float gm = bsum128(g, red, t) * (1.f / 128.f);
  float gv = fmaxf(bsum128(g * g, red, t) * (1.f / 128.f) - gm * gm, 0.f);
  float gh = fmaxf((g - gm) * rsqrtf(gv + 1e-6f) * lncs[t] + lncb[t], 0.f);
  float cm = bsum128(gh * Wc2[t], red, t) + bc2[0];
  if (t < 3) {
    float cd = cd2[(size_t)r * 3 + t] + cd2[(size_t)(1024 + r) * 3 + t];
    float nc = co[(size_t)r * 3 + t] + cd * cm * mk[r];
    out1[(size_t)r * 3 + t] = nc;
  }
}

extern "C" void kernel_launch(void* const* d_in, const int* in_sizes, int n_in,
                              void* d_out, int out_size, void* d_ws, size_t ws_size,
                              hipStream_t stream) {
  const float* nf   = (const float*)d_in[0];
  const float* co   = (const float*)d_in[1];
  const float* efo  = (const float*)d_in[2];
  const float* mk   = (const float*)d_in[3];
  const float* We1  = (const float*)d_in[4];
  const float* be1  = (const float*)d_in[5];
  const float* lnes = (const float*)d_in[6];
  const float* lneb = (const float*)d_in[7];
  const float* We2  = (const float*)d_in[8];
  const float* be2  = (const float*)d_in[9];
  const float* Wa   = (const float*)d_in[10];
  const float* ba   = (const float*)d_in[11];
  const float* Wn1  = (const float*)d_in[12];
  const float* bn1  = (const float*)d_in[13];
  const float* lnns = (const float*)d_in[14];
  const float* lnnb = (const float*)d_in[15];
  const float* Wn2  = (const float*)d_in[16];
  const float* bn2  = (const float*)d_in[17];
  const float* Wc1  = (const float*)d_in[18];
  const float* bc1  = (const float*)d_in[19];
  const float* lncs = (const float*)d_in[20];
  const float* lncb = (const float*)d_in[21];
  const float* Wc2  = (const float*)d_in[22];
  const float* bc2  = (const float*)d_in[23];
  const int* eidx   = (const int*)d_in[24];

  float* out0 = (float*)d_out;        // new_node_features [4,256,128]
  float* out1 = out0 + 131072;        // new_coordinates  [4,256,3]
  float* oute = out1 + 3072;          // new_edge_features [4,256,256,128]

  // ws floats: pre_i | pre_j | api | apj | nm2 | cd2 | bpack(bf16) | wpack(bf16)
  const size_t need = (size_t)(131072 + 131072 + 1024 + 1024 + 262144 + 6144) * 4
                    + (16384 + 4096) * 2;
  if (ws_size < need) {
    k_sent777<<<1, 128, 0, stream>>>(out0);
    return;
  }
  float* ws    = (float*)d_ws;
  float* pre_i = ws;
  float* pre_j = pre_i + 131072;
  float* api   = pre_j + 131072;
  float* apj   = api + 1024;
  float* nm2   = apj + 1024;
  float* cd2   = nm2 + 262144;
  ushort_t* bpack = (ushort_t*)(cd2 + 6144);
  ushort_t* wpack = bpack + 16384;

  k_pre<<<1024, 128, 0, stream>>>(nf, We1, be1, Wa, pre_i, pre_j, api, apj);
  k_pack<<<10, 256, 0, stream>>>(We2, We1, bpack, wpack);
  k_edge<<<2048, 512, 0, stream>>>(co, efo, mk, be2, Wa, ba, lnes, lneb, eidx,
                                   pre_i, pre_j, api, apj, bpack, wpack,
                                   oute, nm2, cd2);
  k_node<<<1024, 128, 0, stream>>>(nf, co, mk, Wn1, bn1, lnns, lnnb, Wn2, bn2,
                                   Wc1, bc1, lncs, lncb, Wc2, bc2, nm2, cd2, out0, out1);
}

// Round 10
// 102.298 us; speedup vs baseline: 1.5495x; 1.0239x over previous
//
#include <hip/hip_runtime.h>
#include <hip/hip_bf16.h>

// EGNN layer, MI355X. B=4, N=256, H=128, E=16, EIN=273. All I/O float32.
// Round 10: FULLY WAVE-INDEPENDENT k_edge. Phase 1 (h1^T = Wx^T x [ef|d2]^T,
// one lane = one edge row x 32 chans) -> in-register LN -> bf16 pack ->
// phase-2 B-frags rebuilt via 4-lane shuffle transpose (no h1 LDS, no mid
// barriers) -> EM^T = We2^T x H1^T -> nontemporal f32x4 stores. One final
// barrier for nm2/cd2 tree reductions. Deterministic fixed-order only.

typedef unsigned short ushort_t;
typedef __attribute__((ext_vector_type(8))) short short8;
typedef __attribute__((ext_vector_type(4))) float f32x4;
typedef __attribute__((ext_vector_type(4))) unsigned int uint32x4;

__device__ __forceinline__ ushort_t f2bf(float f) {
  unsigned int x = __builtin_bit_cast(unsigned int, f);
  x += 0x7fffu + ((x >> 16) & 1u);
  return (ushort_t)(x >> 16);
}
__device__ __forceinline__ unsigned int pack2bf(float a, float b) {
  return (unsigned int)f2bf(a) | ((unsigned int)f2bf(b) << 16);
}

__global__ void k_sent777(float* out0) { out0[threadIdx.x] = 777.f; }

// ---------------- kernel 1: per-node pre-projections ----------------
__global__ __launch_bounds__(128)
void k_pre(const float* nf, const float* We1, const float* be1,
           const float* Wa, float* pre_i, float* pre_j, float* api, float* apj) {
  int r = blockIdx.x, t = threadIdx.x;
  __shared__ float nfv[128];
  __shared__ float red[4];
  nfv[t] = nf[(size_t)r * 128 + t];
  __syncthreads();
  float s1 = be1[t], s2 = 0.f;
  for (int c = 0; c < 128; ++c) {
    float x = nfv[c];
    s1 += x * We1[c * 128 + t];
    s2 += x * We1[(128 + c) * 128 + t];
  }
  pre_i[(size_t)r * 128 + t] = s1;
  pre_j[(size_t)r * 128 + t] = s2;
  float t1 = nfv[t] * Wa[t];
  float t2 = nfv[t] * Wa[128 + t];
#pragma unroll
  for (int o = 32; o > 0; o >>= 1) { t1 += __shfl_down(t1, o); t2 += __shfl_down(t2, o); }
  if ((t & 63) == 0) { red[(t >> 6) * 2] = t1; red[(t >> 6) * 2 + 1] = t2; }
  __syncthreads();
  if (t == 0) { api[r] = red[0] + red[2]; apj[r] = red[1] + red[3]; }
}

// ---------------- kernel 2: pack We2 (bpack) and Wx^T (wpack) ----------------
__global__ __launch_bounds__(256)
void k_pack(const float* We2, const float* We1, ushort_t* bpack, ushort_t* wpack) {
  int t = blockIdx.x * 256 + threadIdx.x;
  if (t < 2048) {
    int ks = t >> 9, mt = (t >> 6) & 7, l = t & 63;
    int kb = ks * 32 + (l >> 4) * 8, col = mt * 16 + (l & 15);
#pragma unroll
    for (int e = 0; e < 8; ++e) bpack[t * 8 + e] = f2bf(We2[(kb + e) * 128 + col]);
  } else if (t < 2560) {
    int q = t - 2048;
    int mt = q >> 6, l = q & 63;
    int chan = mt * 16 + (l & 15), kb = (l >> 4) * 8;
#pragma unroll
    for (int e = 0; e < 8; ++e) {
      int k = kb + e;
      float wv = 0.f;
      if (k < 16) wv = We1[(257 + k) * 128 + chan];
      else if (k == 16) wv = We1[256 * 128 + chan];
      wpack[q * 8 + e] = f2bf(wv);
    }
  }
}

// ---------------- kernel 3: edge MLP + attention + reductions ----------------
// grid 2048: block = (r = b*256+i, half of j). 512 threads = 8 waves, each
// wave fully independent (16 edge rows end-to-end) until the final reduction.
__global__ __launch_bounds__(512, 4)
void k_edge(const float* co, const float* efo, const float* mk,
            const float* be2, const float* Wa, const float* ba,
            const float* lnes, const float* lneb, const int* eidx,
            const float* pre_i, const float* pre_j, const float* api, const float* apj,
            const ushort_t* bpack, const ushort_t* wpack,
            float* oute, float* nm2, float* cd2) {
  __shared__ float nmp[8][128];
  __shared__ float cred[8][3];

  const int bx = blockIdx.x;
  const int r = bx >> 1, half = bx & 1;
  const int b = r >> 8;
  const int t = threadIdx.x;          // 0..511
  const int lane = t & 63, w = t >> 6;
  const int s4 = lane >> 4, li = lane & 15;
  const int row = w * 16 + li;        // edge row in tile (0..127)
  const int j = half * 128 + row;
  const int gj = b * 256 + j;

  // ---- coords / d2 ----
  float dx = co[r * 3 + 0] - co[gj * 3 + 0];
  float dy = co[r * 3 + 1] - co[gj * 3 + 1];
  float dz = co[r * 3 + 2] - co[gj * 3 + 2];
  float d2 = dx * dx + dy * dy + dz * dz;

  // ---- B-frag ([ef|d2|pad]^T) + attention partial dot ----
  short8 bfr = (short8){0, 0, 0, 0, 0, 0, 0, 0};
  float dot = 0.f;
  if (s4 < 2) {
    const float* efp = efo + ((size_t)r * 256 + j) * 16 + s4 * 8;
    f32x4 a0 = *reinterpret_cast<const f32x4*>(efp);
    f32x4 a1 = *reinterpret_cast<const f32x4*>(efp + 4);
#pragma unroll
    for (int x = 0; x < 4; ++x) { bfr[x] = (short)f2bf(a0[x]); bfr[4 + x] = (short)f2bf(a1[x]); }
    const float* wap = Wa + 257 + s4 * 8;
#pragma unroll
    for (int x = 0; x < 4; ++x) dot += a0[x] * wap[x] + a1[x] * wap[4 + x];
  } else if (s4 == 2) {
    bfr[0] = (short)f2bf(d2);
    dot = api[r] + apj[gj] + ba[0] + d2 * Wa[256];
  }
  dot += __shfl_xor(dot, 16);
  dot += __shfl_xor(dot, 32);
  float att = 1.f / (1.f + __expf(-dot));
  float aw = att * (float)eidx[(size_t)r * 256 + j];
  const float wgt = aw * mk[r] * mk[gj];

  // ---- coord-dir reduction (count each row once via s4==0) ----
  {
    float invn = rsqrtf(d2 + 1e-8f);
    float c0 = (s4 == 0) ? dx * invn * aw : 0.f;
    float c1 = (s4 == 0) ? dy * invn * aw : 0.f;
    float c2 = (s4 == 0) ? dz * invn * aw : 0.f;
#pragma unroll
    for (int o = 1; o < 64; o <<= 1) {
      c0 += __shfl_xor(c0, o); c1 += __shfl_xor(c1, o); c2 += __shfl_xor(c2, o);
    }
    if (lane == 0) { cred[w][0] = c0; cred[w][1] = c1; cred[w][2] = c2; }
  }

  // ---- phase 1 MFMA: acc1[mt] = h1^T (lane: row=li-col, chans mt*16+s4*4+x) ----
  f32x4 acc1[8];
#pragma unroll
  for (int mt = 0; mt < 8; ++mt) {
    short8 wfr = *reinterpret_cast<const short8*>(wpack + ((size_t)(mt * 64 + lane)) * 8);
    acc1[mt] = __builtin_amdgcn_mfma_f32_16x16x32_bf16(
        wfr, bfr, (f32x4){0.f, 0.f, 0.f, 0.f}, 0, 0, 0);
  }

  // ---- add pre_i + pre_j (coalesced f32x4), in-register LN stats ----
  const float* pir = pre_i + (size_t)r * 128;
  const float* pjr = pre_j + (size_t)gj * 128;
  float s = 0.f, ss = 0.f;
#pragma unroll
  for (int mt = 0; mt < 8; ++mt) {
    const int c0i = mt * 16 + s4 * 4;
    f32x4 pj = *reinterpret_cast<const f32x4*>(pjr + c0i);
    f32x4 pi = *reinterpret_cast<const f32x4*>(pir + c0i);
    acc1[mt] += pi + pj;
#pragma unroll
    for (int x = 0; x < 4; ++x) { s += acc1[mt][x]; ss += acc1[mt][x] * acc1[mt][x]; }
  }
  s += __shfl_xor(s, 16);  s += __shfl_xor(s, 32);
  ss += __shfl_xor(ss, 16); ss += __shfl_xor(ss, 32);
  const float mean = s * (1.f / 128.f);
  const float var = fmaxf(ss * (1.f / 128.f) - mean * mean, 0.f);
  const float rsv = rsqrtf(var + 1e-6f);

  // ---- apply LN + ReLU in-register, pack to bf16 pairs ----
  unsigned int plo[8], phi[8];
#pragma unroll
  for (int mt = 0; mt < 8; ++mt) {
    const int c0i = mt * 16 + s4 * 4;
    f32x4 ln4 = *reinterpret_cast<const f32x4*>(lnes + c0i);
    f32x4 lb4 = *reinterpret_cast<const f32x4*>(lneb + c0i);
    float g[4];
#pragma unroll
    for (int x = 0; x < 4; ++x)
      g[x] = fmaxf((acc1[mt][x] - mean) * rsv * ln4[x] + lb4[x], 0.f);
    plo[mt] = pack2bf(g[0], g[1]);
    phi[mt] = pack2bf(g[2], g[3]);
  }

  // ---- phase 2: EM^T = We2^T (A) x H1^T (B); B-frags via 4-lane shuffle
  //      transpose: chan c = ks*32+s4*8+e lives in lane srcA/srcB (same li),
  //      mt_src = 2*ks + (s4>>1), x = e&3. srcA = (s4&1)*32+li, srcB = srcA+16.
  f32x4 acc[8];
#pragma unroll
  for (int mt = 0; mt < 8; ++mt) acc[mt] = (f32x4){0.f, 0.f, 0.f, 0.f};

  const int srcA = (s4 & 1) * 32 + li;
  const int srcB = srcA + 16;
  const bool selLo = (s4 < 2);
#pragma unroll
  for (int ks = 0; ks < 4; ++ks) {
    const int m0 = 2 * ks, m1 = 2 * ks + 1;
    unsigned int aL0 = (unsigned int)__shfl((int)plo[m0], srcA);
    unsigned int aH0 = (unsigned int)__shfl((int)phi[m0], srcA);
    unsigned int bL0 = (unsigned int)__shfl((int)plo[m0], srcB);
    unsigned int bH0 = (unsigned int)__shfl((int)phi[m0], srcB);
    unsigned int aL1 = (unsigned int)__shfl((int)plo[m1], srcA);
    unsigned int aH1 = (unsigned int)__shfl((int)phi[m1], srcA);
    unsigned int bL1 = (unsigned int)__shfl((int)plo[m1], srcB);
    unsigned int bH1 = (unsigned int)__shfl((int)phi[m1], srcB);
    uint32x4 hu;
    hu.x = selLo ? aL0 : aL1;   // e0,e1
    hu.y = selLo ? aH0 : aH1;   // e2,e3
    hu.z = selLo ? bL0 : bL1;   // e4,e5
    hu.w = selLo ? bH0 : bH1;   // e6,e7
    short8 hfr = __builtin_bit_cast(short8, hu);
#pragma unroll
    for (int mt = 0; mt < 8; ++mt) {
      short8 afr = *reinterpret_cast<const short8*>(bpack + (((ks * 8 + mt) * 64 + lane) * 8));
      acc[mt] = __builtin_amdgcn_mfma_f32_16x16x32_bf16(afr, hfr, acc[mt], 0, 0, 0);
    }
  }

  // ---- epilogue: nontemporal coalesced stores + att-weighted reduce ----
  const size_t obase = ((size_t)r * 256 + half * 128) * 128;
  const int mq = s4 * 4;
  float pm[8][4];
#pragma unroll
  for (int mt = 0; mt < 8; ++mt) {
    f32x4 b4 = *reinterpret_cast<const f32x4*>(be2 + mt * 16 + mq);
    f32x4 val = acc[mt] + b4;
    __builtin_nontemporal_store(
        val, reinterpret_cast<f32x4*>(oute + obase + (size_t)row * 128 + mt * 16 + mq));
#pragma unroll
    for (int x = 0; x < 4; ++x) pm[mt][x] = val[x] * wgt;
  }
#pragma unroll
  for (int mt = 0; mt < 8; ++mt)
#pragma unroll
    for (int x = 0; x < 4; ++x) {
      float v = pm[mt][x];
      v += __shfl_xor(v, 1); v += __shfl_xor(v, 2);
      v += __shfl_xor(v, 4); v += __shfl_xor(v, 8);
      pm[mt][x] = v;
    }
  if (li == 0) {
#pragma unroll
    for (int mt = 0; mt < 8; ++mt)
#pragma unroll
      for (int x = 0; x < 4; ++x) nmp[w][mt * 16 + mq + x] = pm[mt][x];
  }
  __syncthreads();
  if (t == 0) {
#pragma unroll
    for (int d = 0; d < 3; ++d)
      cd2[(size_t)(half * 1024 + r) * 3 + d] =
          ((cred[0][d] + cred[1][d]) + (cred[2][d] + cred[3][d]))
        + ((cred[4][d] + cred[5][d]) + (cred[6][d] + cred[7][d]));
  }
  if (t < 128) {
    float acc8 = ((nmp[0][t] + nmp[1][t]) + (nmp[2][t] + nmp[3][t]))
               + ((nmp[4][t] + nmp[5][t]) + (nmp[6][t] + nmp[7][t]));
    nm2[(size_t)(half * 1024 + r) * 128 + t] = acc8;
  }
}

// ---------------- kernel 4: node MLP + coord MLP + outputs ----------------
__device__ __forceinline__ float bsum128(float v, float* red, int t) {
#pragma unroll
  for (int o = 32; o > 0; o >>= 1) v += __shfl_down(v, o);
  __syncthreads();
  if ((t & 63) == 0) red[t >> 6] = v;
  __syncthreads();
  return red[0] + red[1];
}

__global__ __launch_bounds__(128)
void k_node(const float* nf, const float* co, const float* mk,
            const float* Wn1, const float* bn1, const float* lnns, const float* lnnb,
            const float* Wn2, const float* bn2,
            const float* Wc1, const float* bc1, const float* lncs, const float* lncb,
            const float* Wc2, const float* bc2,
            const float* nm2, const float* cd2,
            float* out0, float* out1) {
  int r = blockIdx.x, t = threadIdx.x;
  __shared__ float nin[256];
  __shared__ float hf[128];
  __shared__ float red[2];
  float nfv = nf[(size_t)r * 128 + t];
  float nmv = nm2[(size_t)r * 128 + t] + nm2[(size_t)(1024 + r) * 128 + t];
  nin[t] = nfv; nin[128 + t] = nmv;
  __syncthreads();
  float s1 = bn1[t];
  for (int c = 0; c < 256; ++c) s1 += nin[c] * Wn1[c * 128 + t];
  float mean = bsum128(s1, red, t) * (1.f / 128.f);
  float var = fmaxf(bsum128(s1 * s1, red, t) * (1.f / 128.f) - mean * mean, 0.f);
  float hv = (s1 - mean) * rsqrtf(var + 1e-6f) * lnns[t] + lnnb[t];
  hv = fmaxf(hv, 0.f);
  hf[t] = hv;
  __syncthreads();
  float o1 = bn2[t] + nfv;  // residual
  for (int c = 0; c < 128; ++c) o1 += hf[c] * Wn2[c * 128 + t];
  out0[(size_t)r * 128 + t] = o1;
  float g = bc1[t];
  for (int c = 0; c < 128; ++c) g += nin[128 + c] * Wc1[c * 128 + t];
  float gm = bsum128(g, red, t) * (1.f / 128.f);
  float gv = fmaxf(bsum128(g * g, red, t) * (1.f / 128.f) - gm * gm, 0.f);
  float gh = fmaxf((g - gm) * rsqrtf(gv + 1e-6f) * lncs[t] + lncb[t], 0.f);
  float cm = bsum128(gh * Wc2[t], red, t) + bc2[0];
  if (t < 3) {
    float cd = cd2[(size_t)r * 3 + t] + cd2[(size_t)(1024 + r) * 3 + t];
    float nc = co[(size_t)r * 3 + t] + cd * cm * mk[r];
    out1[(size_t)r * 3 + t] = nc;
  }
}

extern "C" void kernel_launch(void* const* d_in, const int* in_sizes, int n_in,
                              void* d_out, int out_size, void* d_ws, size_t ws_size,
                              hipStream_t stream) {
  const float* nf   = (const float*)d_in[0];
  const float* co   = (const float*)d_in[1];
  const float* efo  = (const float*)d_in[2];
  const float* mk   = (const float*)d_in[3];
  const float* We1  = (const float*)d_in[4];
  const float* be1  = (const float*)d_in[5];
  const float* lnes = (const float*)d_in[6];
  const float* lneb = (const float*)d_in[7];
  const float* We2  = (const float*)d_in[8];
  const float* be2  = (const float*)d_in[9];
  const float* Wa   = (const float*)d_in[10];
  const float* ba   = (const float*)d_in[11];
  const float* Wn1  = (const float*)d_in[12];
  const float* bn1  = (const float*)d_in[13];
  const float* lnns = (const float*)d_in[14];
  const float* lnnb = (const float*)d_in[15];
  const float* Wn2  = (const float*)d_in[16];
  const float* bn2  = (const float*)d_in[17];
  const float* Wc1  = (const float*)d_in[18];
  const float* bc1  = (const float*)d_in[19];
  const float* lncs = (const float*)d_in[20];
  const float* lncb = (const float*)d_in[21];
  const float* Wc2  = (const float*)d_in[22];
  const float* bc2  = (const float*)d_in[23];
  const int* eidx   = (const int*)d_in[24];

  float* out0 = (float*)d_out;        // new_node_features [4,256,128]
  float* out1 = out0 + 131072;        // new_coordinates  [4,256,3]
  float* oute = out1 + 3072;          // new_edge_features [4,256,256,128]

  // ws floats: pre_i | pre_j | api | apj | nm2 | cd2 | bpack(bf16) | wpack(bf16)
  const size_t need = (size_t)(131072 + 131072 + 1024 + 1024 + 262144 + 6144) * 4
                    + (16384 + 4096) * 2;
  if (ws_size < need) {
    k_sent777<<<1, 128, 0, stream>>>(out0);
    return;
  }
  float* ws    = (float*)d_ws;
  float* pre_i = ws;
  float* pre_j = pre_i + 131072;
  float* api   = pre_j + 131072;
  float* apj   = api + 1024;
  float* nm2   = apj + 1024;
  float* cd2   = nm2 + 262144;
  ushort_t* bpack = (ushort_t*)(cd2 + 6144);
  ushort_t* wpack = bpack + 16384;

  k_pre<<<1024, 128, 0, stream>>>(nf, We1, be1, Wa, pre_i, pre_j, api, apj);
  k_pack<<<10, 256, 0, stream>>>(We2, We1, bpack, wpack);
  k_edge<<<2048, 512, 0, stream>>>(co, efo, mk, be2, Wa, ba, lnes, lneb, eidx,
                                   pre_i, pre_j, api, apj, bpack, wpack,
                                   oute, nm2, cd2);
  k_node<<<1024, 128, 0, stream>>>(nf, co, mk, Wn1, bn1, lnns, lnnb, Wn2, bn2,
                                   Wc1, bc1, lncs, lncb, Wc2, bc2, nm2, cd2, out0, out1);
}